// Round 5
// baseline (318.826 us; speedup 1.0000x reference)
//
#include <hip/hip_runtime.h>
#include <math.h>

#define Bsz  64
#define Cch  2048
#define Kdim 768
#define Ssp  361

// ---------------------------------------------------------------------------
// K1: qT[c][b] = dot(text[b,:], W[c,:]) + bias[c]
// grid = (256, 8) x 256 threads; wave owns 2 channels (W rows in 24 VGPRs),
// 8 batches per wave processed in pairs -> 6 float4 loads + 4 independent
// FMA/shuffle chains in flight. 32 waves/CU.
// ---------------------------------------------------------------------------
__global__ __launch_bounds__(256) void k_qgemm(
    const float* __restrict__ text, const float* __restrict__ W,
    const float* __restrict__ bias, float* __restrict__ qT)
{
    const int lane = threadIdx.x & 63;
    const int wv   = threadIdx.x >> 6;
    const int c0   = blockIdx.x * 8 + wv * 2;
    const int b0   = blockIdx.y * 8;

    const float4* wA = (const float4*)(W + (size_t)c0 * Kdim);
    const float4* wB = (const float4*)(W + (size_t)(c0 + 1) * Kdim);
    const float4 a0 = wA[lane*3+0], a1 = wA[lane*3+1], a2 = wA[lane*3+2];
    const float4 g0 = wB[lane*3+0], g1 = wB[lane*3+1], g2 = wB[lane*3+2];
    const float biasA = bias[c0], biasB = bias[c0 + 1];

    for (int b = b0; b < b0 + 8; b += 2) {
        const float4* tp = (const float4*)(text + (size_t)b * Kdim);
        const float4* up = (const float4*)(text + (size_t)(b + 1) * Kdim);
        const float4 t0 = tp[lane*3+0], t1 = tp[lane*3+1], t2 = tp[lane*3+2];
        const float4 u0 = up[lane*3+0], u1 = up[lane*3+1], u2 = up[lane*3+2];

        float r00 = a0.x*t0.x + a0.y*t0.y + a0.z*t0.z + a0.w*t0.w
                  + a1.x*t1.x + a1.y*t1.y + a1.z*t1.z + a1.w*t1.w
                  + a2.x*t2.x + a2.y*t2.y + a2.z*t2.z + a2.w*t2.w;
        float r10 = g0.x*t0.x + g0.y*t0.y + g0.z*t0.z + g0.w*t0.w
                  + g1.x*t1.x + g1.y*t1.y + g1.z*t1.z + g1.w*t1.w
                  + g2.x*t2.x + g2.y*t2.y + g2.z*t2.z + g2.w*t2.w;
        float r01 = a0.x*u0.x + a0.y*u0.y + a0.z*u0.z + a0.w*u0.w
                  + a1.x*u1.x + a1.y*u1.y + a1.z*u1.z + a1.w*u1.w
                  + a2.x*u2.x + a2.y*u2.y + a2.z*u2.z + a2.w*u2.w;
        float r11 = g0.x*u0.x + g0.y*u0.y + g0.z*u0.z + g0.w*u0.w
                  + g1.x*u1.x + g1.y*u1.y + g1.z*u1.z + g1.w*u1.w
                  + g2.x*u2.x + g2.y*u2.y + g2.z*u2.z + g2.w*u2.w;
        #pragma unroll
        for (int off = 32; off; off >>= 1) {
            r00 += __shfl_xor(r00, off);
            r10 += __shfl_xor(r10, off);
            r01 += __shfl_xor(r01, off);
            r11 += __shfl_xor(r11, off);
        }
        if (lane == 0) {
            qT[(size_t)c0 * Bsz + b]           = r00 + biasA;
            qT[(size_t)(c0 + 1) * Bsz + b]     = r10 + biasB;
            qT[(size_t)c0 * Bsz + b + 1]       = r01 + biasA;
            qT[(size_t)(c0 + 1) * Bsz + b + 1] = r11 + biasB;
        }
    }
}

// ---------------------------------------------------------------------------
// K2: partial sims — STRUCTURALLY 16-deep. grid (b=64, cg=128) x 384 threads;
// thread = spatial s; block covers 16 channels with straight-line code:
// 16 independent coalesced loads, 16 FMAs, 1 store. No loop for the
// scheduler to collapse (round 3/4 showed it keeps only ~2-4 loads in
// flight when given a loop — VGPR_Count=16). This is the HBM pass (189 MB).
// ---------------------------------------------------------------------------
__global__ __launch_bounds__(384) void k_sims(
    const float* __restrict__ img, const float* __restrict__ qT,
    float* __restrict__ sims_part)
{
    const int b  = blockIdx.x;
    const int cg = blockIdx.y;          // 128 groups of 16 channels
    const int tid = threadIdx.x;

    __shared__ float qL[16];
    if (tid < 16) qL[tid] = qT[(size_t)(cg * 16 + tid) * Bsz + b];
    __syncthreads();

    if (tid < Ssp) {
        const float* base = img + ((size_t)b * Cch + (size_t)cg * 16) * Ssp + tid;
        const float v0  = base[0 * Ssp],  v1  = base[1 * Ssp];
        const float v2  = base[2 * Ssp],  v3  = base[3 * Ssp];
        const float v4  = base[4 * Ssp],  v5  = base[5 * Ssp];
        const float v6  = base[6 * Ssp],  v7  = base[7 * Ssp];
        const float v8  = base[8 * Ssp],  v9  = base[9 * Ssp];
        const float v10 = base[10 * Ssp], v11 = base[11 * Ssp];
        const float v12 = base[12 * Ssp], v13 = base[13 * Ssp];
        const float v14 = base[14 * Ssp], v15 = base[15 * Ssp];
        float acc = qL[0]*v0   + qL[1]*v1   + qL[2]*v2   + qL[3]*v3
                  + qL[4]*v4   + qL[5]*v5   + qL[6]*v6   + qL[7]*v7
                  + qL[8]*v8   + qL[9]*v9   + qL[10]*v10 + qL[11]*v11
                  + qL[12]*v12 + qL[13]*v13 + qL[14]*v14 + qL[15]*v15;
        sims_part[((size_t)b * 128 + cg) * Ssp + tid] = acc;
    }
}

// ---------------------------------------------------------------------------
// K3: weights. grid = 64 blocks x 384 threads; thread = spatial s.
// Sums the 128 partials (16-deep batched, L2-hot), block softmax, writes
// PRE-NORMALIZED weights.
// ---------------------------------------------------------------------------
__global__ __launch_bounds__(384) void k_wts(
    const float* __restrict__ sims_part, float* __restrict__ wts)
{
    const int b   = blockIdx.x;
    const int tid = threadIdx.x;
    const int lane = tid & 63;
    const int wv   = tid >> 6;

    __shared__ float red[6];

    float s0 = -1e30f;
    if (tid < Ssp) {
        const float* sp = sims_part + (size_t)b * 128 * Ssp + tid;
        float a = 0.f;
        for (int g0 = 0; g0 < 128; g0 += 16) {
            float v[16];
            #pragma unroll
            for (int j = 0; j < 16; j++) v[j] = sp[(size_t)(g0 + j) * Ssp];
            #pragma unroll
            for (int j = 0; j < 16; j++) a += v[j];
        }
        s0 = a;
    }

    float m = s0;
    #pragma unroll
    for (int off = 32; off; off >>= 1) m = fmaxf(m, __shfl_xor(m, off));
    if (lane == 0) red[wv] = m;
    __syncthreads();
    m = red[0];
    #pragma unroll
    for (int w = 1; w < 6; w++) m = fmaxf(m, red[w]);
    __syncthreads();

    const float e0 = (tid < Ssp) ? __expf(s0 - m) : 0.f;
    float l = e0;
    #pragma unroll
    for (int off = 32; off; off >>= 1) l += __shfl_xor(l, off);
    if (lane == 0) red[wv] = l;
    __syncthreads();
    l = red[0] + red[1] + red[2] + red[3] + red[4] + red[5];

    if (tid < Ssp)
        wts[(size_t)b * Ssp + tid] = e0 / l;
}

// ---------------------------------------------------------------------------
// K4: weighted pooling. grid (b=64, cg=16) x 256 threads; wave owns 32
// channels processed 4-at-a-time -> 24 outstanding loads, 4 interleaved
// reduce chains. Weights in registers. Coalesced 128-wide store via LDS.
// Second img pass — expected largely L3-resident.
// ---------------------------------------------------------------------------
__global__ __launch_bounds__(256) void k_pool(
    const float* __restrict__ img, const float* __restrict__ wts,
    float* __restrict__ out)
{
    const int b   = blockIdx.x;
    const int cg  = blockIdx.y;
    const int tid = threadIdx.x;
    const int lane = tid & 63;
    const int wv   = tid >> 6;

    __shared__ float outL[128];

    const float* wb = wts + (size_t)b * Ssp;
    const float w0 = wb[lane];
    const float w1 = wb[lane + 64];
    const float w2 = wb[lane + 128];
    const float w3 = wb[lane + 192];
    const float w4 = wb[lane + 256];
    const float w5 = (lane + 320 < Ssp) ? wb[lane + 320] : 0.f;

    const int cbase = cg * 128 + wv * 32;
    for (int cc = 0; cc < 32; cc += 4) {
        const float* p0 = img + ((size_t)b * Cch + cbase + cc) * Ssp;
        const float* p1 = p0 + Ssp;
        const float* p2 = p1 + Ssp;
        const float* p3 = p2 + Ssp;
        float r0, r1, r2, r3;
        {
            float v00=p0[lane],     v01=p0[lane+64],  v02=p0[lane+128],
                  v03=p0[lane+192], v04=p0[lane+256];
            float v10=p1[lane],     v11=p1[lane+64],  v12=p1[lane+128],
                  v13=p1[lane+192], v14=p1[lane+256];
            float v20=p2[lane],     v21=p2[lane+64],  v22=p2[lane+128],
                  v23=p2[lane+192], v24=p2[lane+256];
            float v30=p3[lane],     v31=p3[lane+64],  v32=p3[lane+128],
                  v33=p3[lane+192], v34=p3[lane+256];
            float v05 = 0.f, v15 = 0.f, v25 = 0.f, v35 = 0.f;
            if (lane + 320 < Ssp) {
                v05 = p0[lane+320]; v15 = p1[lane+320];
                v25 = p2[lane+320]; v35 = p3[lane+320];
            }
            r0 = v00*w0 + v01*w1 + v02*w2 + v03*w3 + v04*w4 + v05*w5;
            r1 = v10*w0 + v11*w1 + v12*w2 + v13*w3 + v14*w4 + v15*w5;
            r2 = v20*w0 + v21*w1 + v22*w2 + v23*w3 + v24*w4 + v25*w5;
            r3 = v30*w0 + v31*w1 + v32*w2 + v33*w3 + v34*w4 + v35*w5;
        }
        #pragma unroll
        for (int off = 32; off; off >>= 1) {
            r0 += __shfl_xor(r0, off);
            r1 += __shfl_xor(r1, off);
            r2 += __shfl_xor(r2, off);
            r3 += __shfl_xor(r3, off);
        }
        if (lane == 0) {
            outL[wv * 32 + cc]     = r0;
            outL[wv * 32 + cc + 1] = r1;
            outL[wv * 32 + cc + 2] = r2;
            outL[wv * 32 + cc + 3] = r3;
        }
    }
    __syncthreads();
    if (tid < 128)
        out[(size_t)b * Cch + cg * 128 + tid] = outL[tid];
}

// ---------------------------------------------------------------------------
extern "C" void kernel_launch(void* const* d_in, const int* in_sizes, int n_in,
                              void* d_out, int out_size, void* d_ws, size_t ws_size,
                              hipStream_t stream) {
    const float* text = (const float*)d_in[0];   // [64, 768]
    const float* img  = (const float*)d_in[1];   // [64, 2048, 19, 19]
    const float* W    = (const float*)d_in[2];   // [2048, 768]
    const float* bias = (const float*)d_in[3];   // [2048]
    float* out = (float*)d_out;                  // [64, 2048]

    // ws: qT (2048*64 = 512 KB) + sims_part (64*128*361 = 11.8 MB) + wts (90 KB)
    float* qT        = (float*)d_ws;
    float* sims_part = qT + (size_t)Cch * Bsz;
    float* wts       = sims_part + (size_t)Bsz * 128 * Ssp;

    k_qgemm<<<dim3(256, 8),   256, 0, stream>>>(text, W, bias, qT);
    k_sims <<<dim3(Bsz, 128), 384, 0, stream>>>(img, qT, sims_part);
    k_wts  <<<dim3(Bsz),      384, 0, stream>>>(sims_part, wts);
    k_pool <<<dim3(Bsz, 16),  256, 0, stream>>>(img, wts, out);
}

// Round 6
// 316.516 us; speedup vs baseline: 1.0073x; 1.0073x over previous
//
#include <hip/hip_runtime.h>
#include <math.h>

#define Bsz  64
#define Cch  2048
#define Kdim 768
#define Ssp  361
#define CPB  16                      // channels per block (sims/pool staging)
#define REGF (CPB * Ssp)             // 5776 floats = 23104 B per block slice
#define NFULL 22                     // 22 full 1KB DMA issues ...
#define NTAIL 36                     // ... + 1 tail issue with 36 active lanes

// ---------------------------------------------------------------------------
// Async global->LDS DMA, 16 B per lane per issue. DMA consumes no VGPRs, so
// the compiler cannot sink/serialize it (rounds 3-5 showed VGPR-minimizing
// scheduling keeps only ~2 plain loads in flight -> 2 TB/s latency wall).
// LDS dest semantics: wave-uniform base + lane*16 (m104/m108).
// ---------------------------------------------------------------------------
__device__ __forceinline__ void dma16(const float* g, float* l) {
    __builtin_amdgcn_global_load_lds(
        (const __attribute__((address_space(1))) void*)(g),
        (__attribute__((address_space(3))) void*)(l),
        16, 0, 0);
}

// Stage one 23104 B slice (16 channels x 361 floats, 16 B-aligned) into LDS.
// 6 waves split 23 issues; each wave then drains its own vmcnt.
__device__ __forceinline__ void stage_slice(const float* region, float* lds,
                                            int wv, int lane) {
    for (int i = wv; i < NFULL + 1; i += 6) {
        if (i < NFULL || lane < NTAIL)
            dma16(region + i * 256 + lane * 4, lds + i * 256);
    }
    asm volatile("s_waitcnt vmcnt(0)" ::: "memory");
}

// ---------------------------------------------------------------------------
// K1: qT[c][b] = dot(text[b,:], W[c,:]) + bias[c]
// grid = (256, 8) x 256; wave owns 2 channels, 8 batches in pairs. ~8 us.
// ---------------------------------------------------------------------------
__global__ __launch_bounds__(256) void k_qgemm(
    const float* __restrict__ text, const float* __restrict__ W,
    const float* __restrict__ bias, float* __restrict__ qT)
{
    const int lane = threadIdx.x & 63;
    const int wv   = threadIdx.x >> 6;
    const int c0   = blockIdx.x * 8 + wv * 2;
    const int b0   = blockIdx.y * 8;

    const float4* wA = (const float4*)(W + (size_t)c0 * Kdim);
    const float4* wB = (const float4*)(W + (size_t)(c0 + 1) * Kdim);
    const float4 a0 = wA[lane*3+0], a1 = wA[lane*3+1], a2 = wA[lane*3+2];
    const float4 g0 = wB[lane*3+0], g1 = wB[lane*3+1], g2 = wB[lane*3+2];
    const float biasA = bias[c0], biasB = bias[c0 + 1];

    for (int b = b0; b < b0 + 8; b += 2) {
        const float4* tp = (const float4*)(text + (size_t)b * Kdim);
        const float4* up = (const float4*)(text + (size_t)(b + 1) * Kdim);
        const float4 t0 = tp[lane*3+0], t1 = tp[lane*3+1], t2 = tp[lane*3+2];
        const float4 u0 = up[lane*3+0], u1 = up[lane*3+1], u2 = up[lane*3+2];

        float r00 = a0.x*t0.x + a0.y*t0.y + a0.z*t0.z + a0.w*t0.w
                  + a1.x*t1.x + a1.y*t1.y + a1.z*t1.z + a1.w*t1.w
                  + a2.x*t2.x + a2.y*t2.y + a2.z*t2.z + a2.w*t2.w;
        float r10 = g0.x*t0.x + g0.y*t0.y + g0.z*t0.z + g0.w*t0.w
                  + g1.x*t1.x + g1.y*t1.y + g1.z*t1.z + g1.w*t1.w
                  + g2.x*t2.x + g2.y*t2.y + g2.z*t2.z + g2.w*t2.w;
        float r01 = a0.x*u0.x + a0.y*u0.y + a0.z*u0.z + a0.w*u0.w
                  + a1.x*u1.x + a1.y*u1.y + a1.z*u1.z + a1.w*u1.w
                  + a2.x*u2.x + a2.y*u2.y + a2.z*u2.z + a2.w*u2.w;
        float r11 = g0.x*u0.x + g0.y*u0.y + g0.z*u0.z + g0.w*u0.w
                  + g1.x*u1.x + g1.y*u1.y + g1.z*u1.z + g1.w*u1.w
                  + g2.x*u2.x + g2.y*u2.y + g2.z*u2.z + g2.w*u2.w;
        #pragma unroll
        for (int off = 32; off; off >>= 1) {
            r00 += __shfl_xor(r00, off);
            r10 += __shfl_xor(r10, off);
            r01 += __shfl_xor(r01, off);
            r11 += __shfl_xor(r11, off);
        }
        if (lane == 0) {
            qT[(size_t)c0 * Bsz + b]           = r00 + biasA;
            qT[(size_t)(c0 + 1) * Bsz + b]     = r10 + biasB;
            qT[(size_t)c0 * Bsz + b + 1]       = r01 + biasA;
            qT[(size_t)(c0 + 1) * Bsz + b + 1] = r11 + biasB;
        }
    }
}

// ---------------------------------------------------------------------------
// K2: partial sims via DMA-staged LDS. grid (b=64, cg=128) x 384.
// Stage 16-channel slice (23 KB) with global_load_lds, then thread s<361
// does 16 conflict-free LDS reads + FMAs. This is the HBM pass (189 MB).
// ---------------------------------------------------------------------------
__global__ __launch_bounds__(384) void k_sims(
    const float* __restrict__ img, const float* __restrict__ qT,
    float* __restrict__ sims_part)
{
    const int b  = blockIdx.x;
    const int cg = blockIdx.y;
    const int tid = threadIdx.x;
    const int lane = tid & 63;
    const int wv   = tid >> 6;

    __shared__ float lds[REGF];
    __shared__ float qL[CPB];

    if (tid < CPB) qL[tid] = qT[(size_t)(cg * CPB + tid) * Bsz + b];

    const float* region = img + ((size_t)b * Cch + (size_t)cg * CPB) * Ssp;
    stage_slice(region, lds, wv, lane);
    __syncthreads();

    if (tid < Ssp) {
        float acc = 0.f;
        #pragma unroll
        for (int c = 0; c < CPB; c++)
            acc += qL[c] * lds[c * Ssp + tid];
        sims_part[((size_t)b * 128 + cg) * Ssp + tid] = acc;
    }
}

// ---------------------------------------------------------------------------
// K3: weights. grid = 64 x 384; sums the 128 partials (L2-hot), block
// softmax, writes PRE-NORMALIZED weights.
// ---------------------------------------------------------------------------
__global__ __launch_bounds__(384) void k_wts(
    const float* __restrict__ sims_part, float* __restrict__ wts)
{
    const int b   = blockIdx.x;
    const int tid = threadIdx.x;
    const int lane = tid & 63;
    const int wv   = tid >> 6;

    __shared__ float red[6];

    float s0 = -1e30f;
    if (tid < Ssp) {
        const float* sp = sims_part + (size_t)b * 128 * Ssp + tid;
        float a = 0.f;
        for (int g0 = 0; g0 < 128; g0 += 16) {
            float v[16];
            #pragma unroll
            for (int j = 0; j < 16; j++) v[j] = sp[(size_t)(g0 + j) * Ssp];
            #pragma unroll
            for (int j = 0; j < 16; j++) a += v[j];
        }
        s0 = a;
    }

    float m = s0;
    #pragma unroll
    for (int off = 32; off; off >>= 1) m = fmaxf(m, __shfl_xor(m, off));
    if (lane == 0) red[wv] = m;
    __syncthreads();
    m = red[0];
    #pragma unroll
    for (int w = 1; w < 6; w++) m = fmaxf(m, red[w]);
    __syncthreads();

    const float e0 = (tid < Ssp) ? __expf(s0 - m) : 0.f;
    float l = e0;
    #pragma unroll
    for (int off = 32; off; off >>= 1) l += __shfl_xor(l, off);
    if (lane == 0) red[wv] = l;
    __syncthreads();
    l = red[0] + red[1] + red[2] + red[3] + red[4] + red[5];

    if (tid < Ssp)
        wts[(size_t)b * Ssp + tid] = e0 / l;
}

// ---------------------------------------------------------------------------
// K4: weighted pooling via DMA-staged LDS. grid (b=64, cg=128) x 384.
// Same 23 KB staging; then lane -> (c = lane&15, slice = lane>>4) mapping:
// each lane accumulates its channel over its s-slice (6 waves split the
// slice), 2 shuffles + tiny LDS combine -> 16 outputs per block.
// Second img pass — largely L3-resident.
// ---------------------------------------------------------------------------
__global__ __launch_bounds__(384) void k_pool(
    const float* __restrict__ img, const float* __restrict__ wts,
    float* __restrict__ out)
{
    const int b   = blockIdx.x;
    const int cg  = blockIdx.y;
    const int tid = threadIdx.x;
    const int lane = tid & 63;
    const int wv   = tid >> 6;

    __shared__ float lds[REGF];
    __shared__ float wL[Ssp];
    __shared__ float partial[6 * CPB];

    if (tid < Ssp) wL[tid] = wts[(size_t)b * Ssp + tid];

    const float* region = img + ((size_t)b * Cch + (size_t)cg * CPB) * Ssp;
    stage_slice(region, lds, wv, lane);
    __syncthreads();

    // lane -> channel c, s-slice sl; slices: [0,91),[91,181),[181,271),[271,361)
    const int c    = lane & 15;
    const int sl   = lane >> 4;
    const int s_lo = sl * 90 + (sl > 0 ? 1 : 0);
    const int s_hi = s_lo + (sl > 0 ? 90 : 91);

    float p = 0.f;
    for (int s = s_lo + wv; s < s_hi; s += 6)
        p += lds[c * Ssp + s] * wL[s];     // banks hop by 361%32=9 — conflict-free

    p += __shfl_xor(p, 16);                // combine 4 slices (same c)
    p += __shfl_xor(p, 32);
    if (lane < CPB) partial[wv * CPB + lane] = p;
    __syncthreads();

    if (tid < CPB) {
        float r = partial[tid];
        #pragma unroll
        for (int w = 1; w < 6; w++) r += partial[w * CPB + tid];
        out[(size_t)b * Cch + (size_t)cg * CPB + tid] = r;
    }
}

// ---------------------------------------------------------------------------
extern "C" void kernel_launch(void* const* d_in, const int* in_sizes, int n_in,
                              void* d_out, int out_size, void* d_ws, size_t ws_size,
                              hipStream_t stream) {
    const float* text = (const float*)d_in[0];   // [64, 768]
    const float* img  = (const float*)d_in[1];   // [64, 2048, 19, 19]
    const float* W    = (const float*)d_in[2];   // [2048, 768]
    const float* bias = (const float*)d_in[3];   // [2048]
    float* out = (float*)d_out;                  // [64, 2048]

    // ws: qT (512 KB) + sims_part (11.8 MB) + wts (90 KB)
    float* qT        = (float*)d_ws;
    float* sims_part = qT + (size_t)Cch * Bsz;
    float* wts       = sims_part + (size_t)Bsz * 128 * Ssp;

    k_qgemm<<<dim3(256, 8),   256, 0, stream>>>(text, W, bias, qT);
    k_sims <<<dim3(Bsz, 128), 384, 0, stream>>>(img, qT, sims_part);
    k_wts  <<<dim3(Bsz),      384, 0, stream>>>(sims_part, wts);
    k_pool <<<dim3(Bsz, 128), 384, 0, stream>>>(img, wts, out);
}